// Round 7
// baseline (523.873 us; speedup 1.0000x reference)
//
#include <hip/hip_runtime.h>
#include <hip/hip_cooperative_groups.h>

namespace cg = cooperative_groups;

#define N_NODES 100000
#define DEG 16
#define IN_F 128
#define OUT_F 64
#define E_EDGES (N_NODES * DEG)
#define TILES 1563          // ceil(N_NODES / 64)
#define GEMM_GRID 768       // fallback persistent-GEMM grid (R5)

typedef __bf16 bf16x8 __attribute__((ext_vector_type(8)));
typedef unsigned short u16x8 __attribute__((ext_vector_type(8)));
typedef float f32x4 __attribute__((ext_vector_type(4)));
typedef unsigned int u32x4 __attribute__((ext_vector_type(4)));

union BF8 { u16x8 u; bf16x8 b; };

__device__ inline float lo_bf(unsigned int u) {
    union { unsigned int i; float f; } v; v.i = u << 16; return v.f;
}
__device__ inline float hi_bf(unsigned int u) {
    union { unsigned int i; float f; } v; v.i = u & 0xFFFF0000u; return v.f;
}
__device__ inline unsigned short f2bf(float f) {
    union { float f; unsigned int i; } v; v.f = f;
    return (unsigned short)((v.i + 0x7FFFu + ((v.i >> 16) & 1u)) >> 16);
}
__device__ inline unsigned int packbf(float a, float b) {
    return (unsigned int)f2bf(a) | ((unsigned int)f2bf(b) << 16);
}

// A fragment direct from global: 8 consecutive f32 -> bf16x8 (same f2bf bits
// as the ldsA path)
__device__ inline bf16x8 mk_afrag(const float* ap) {
    f32x4 a0 = *(const f32x4*)ap;
    f32x4 a1 = *(const f32x4*)(ap + 4);
    BF8 r;
    r.u[0] = f2bf(a0[0]); r.u[1] = f2bf(a0[1]);
    r.u[2] = f2bf(a0[2]); r.u[3] = f2bf(a0[3]);
    r.u[4] = f2bf(a1[0]); r.u[5] = f2bf(a1[1]);
    r.u[6] = f2bf(a1[2]); r.u[7] = f2bf(a1[3]);
    return r.b;
}

__device__ inline void grid_sync_fenced() {
    __builtin_amdgcn_fence(__ATOMIC_RELEASE, "agent");   // L2 writeback (cross-XCD)
    cg::this_grid().sync();
    __builtin_amdgcn_fence(__ATOMIC_ACQUIRE, "agent");   // L1/L2 invalidate
}

// ---------------- Fused cooperative kernel: GEMM -> sync -> AGG -> sync -> OUT
// Phase float sequences are R3-verbatim (bit-identical per node/tile).
__global__ __launch_bounds__(256, 4) void k_fused(
    const float* __restrict__ in, const float* __restrict__ Wh,
    const float* __restrict__ Wl, const int* __restrict__ dst,
    const float* __restrict__ ah, const float* __restrict__ al,
    unsigned int* __restrict__ H, unsigned int* __restrict__ HAGG,
    f32x4* __restrict__ s, float* __restrict__ out)
{
    __shared__ __align__(16) unsigned short ldsW[2][64][136];  // 34816 B only
    const int stride = gridDim.x;

    // W conversion (once per block): coalesced 256-B reads along n
    {
        int n  = threadIdx.x & 63;
        int kg = threadIdx.x >> 6;
        #pragma unroll
        for (int m = 0; m < 2; m++) {
            const float* W = m ? Wl : Wh;
            #pragma unroll
            for (int i = 0; i < 32; i += 2) {
                int k = kg * 32 + i;
                float a = W[k * 64 + n];
                float b = W[(k + 1) * 64 + n];
                *(unsigned int*)&ldsW[m][n][k] = packbf(a, b);
            }
        }
    }
    __syncthreads();

    int wv = threadIdx.x >> 6;
    int lane = threadIdx.x & 63;
    int quad = lane >> 4, c = lane & 15;

    // ---------------- phase 0: GEMM, grid-stride tiles, barrier-free loop ----
    for (int tile = blockIdx.x; tile < TILES; tile += stride) {
        int row0B = tile * 64;
        int arow = row0B + wv * 16 + c;
        const float* ap = in + (size_t)(arow < N_NODES ? arow : N_NODES - 1) * IN_F;

        bf16x8 afrag[4];
        #pragma unroll
        for (int kb = 0; kb < 4; kb++)
            afrag[kb] = mk_afrag(ap + kb * 32 + quad * 8);

        f32x4 acc[2][4];
        #pragma unroll
        for (int m = 0; m < 2; m++)
            #pragma unroll
            for (int t = 0; t < 4; t++) acc[m][t] = (f32x4){0, 0, 0, 0};

        #pragma unroll
        for (int kb = 0; kb < 4; kb++) {
            #pragma unroll
            for (int t = 0; t < 4; t++) {
                int n = t * 16 + c;
                BF8 bh, bl;
                bh.u = *(const u16x8*)&ldsW[0][n][kb * 32 + quad * 8];
                bl.u = *(const u16x8*)&ldsW[1][n][kb * 32 + quad * 8];
                acc[0][t] = __builtin_amdgcn_mfma_f32_16x16x32_bf16(afrag[kb], bh.b, acc[0][t], 0, 0, 0);
                acc[1][t] = __builtin_amdgcn_mfma_f32_16x16x32_bf16(afrag[kb], bl.b, acc[1][t], 0, 0, 0);
            }
        }

        int row0 = row0B + wv * 16;
        #pragma unroll
        for (int r = 0; r < 4; r++) {
            int row = row0 + quad * 4 + r;
            if (row >= N_NODES) continue;
            size_t base = (size_t)row * OUT_F + c;
            #pragma unroll
            for (int t = 0; t < 4; t++)
                H[base + t * 16] = packbf(acc[0][t][r], acc[1][t][r]);
        }
    }

    float a0 = ah[lane], a1 = ah[64 + lane];
    float c0 = al[lane], c1 = al[64 + lane];

    grid_sync_fenced();

    // ---------------- phase 1: HAGG + s (R3 k_agg body verbatim) ----
    for (int grp = blockIdx.x; grp < N_NODES / 4; grp += stride) {
        int node = __builtin_amdgcn_readfirstlane(grp * 4 + wv);
        const int* dp = dst + node * DEG;

        unsigned int hu = H[(size_t)node * 64 + lane];
        float hh = lo_bf(hu);
        float hl = hi_bf(hu);
        float sh = 16.0f * hh;
        float sl = 16.0f * hl;

        #pragma unroll
        for (int half = 0; half < 2; half++) {
            unsigned int u[8];
            #pragma unroll
            for (int t = 0; t < 8; t++) {
                int j = dp[half * 8 + t];
                u[t] = H[(size_t)j * 64 + lane];
            }
            #pragma unroll
            for (int t = 0; t < 8; t++) { sh += lo_bf(u[t]); sl -= hi_bf(u[t]); }
        }
        HAGG[(size_t)node * 64 + lane] = packbf(sh, sl);

        float ph = hh * a0;
        float qh = hh * a1;
        float pl = hl * c0;
        float ql = hl * c1;
        #pragma unroll
        for (int o = 32; o > 0; o >>= 1) {
            ph += __shfl_xor(ph, o);
            qh += __shfl_xor(qh, o);
            pl += __shfl_xor(pl, o);
            ql += __shfl_xor(ql, o);
        }
        if (lane == 0) s[node] = (f32x4){ph, qh, pl, ql};
    }

    grid_sync_fenced();

    // ---------------- phase 2: weighted aggregate + relu6 (R3 k_out verbatim) ----
    for (int grp = blockIdx.x; grp < N_NODES / 4; grp += stride) {
        int node = __builtin_amdgcn_readfirstlane(grp * 4 + wv);
        const int* dp = dst + node * DEG;

        int jl = dp[lane & 15];
        f32x4 si = s[node];
        f32x4 sj = s[jl];
        float xh = si.x + sj.y;
        float xl = si.z + sj.w;
        float lh = xh > 0.0f ? xh : 0.2f * xh;
        float ll = xl > 0.0f ? xl : 0.2f * xl;
        float wh = __expf(-lh);
        float wl = __expf(-ll);
        float rh = wh, rl = wl;
        #pragma unroll
        for (int o = 8; o > 0; o >>= 1) { rh += __shfl_xor(rh, o); rl += __shfl_xor(rl, o); }
        float eh = fminf(wh, 6.0f);
        float el = fminf(wl, 6.0f);

        float acc_h = 0.0f, acc_l = 0.0f;
        #pragma unroll
        for (int half = 0; half < 2; half++) {
            unsigned int u[8];
            float weh[8], wel[8];
            #pragma unroll
            for (int t = 0; t < 8; t++) {
                int j = dp[half * 8 + t];
                u[t] = HAGG[(size_t)j * 64 + lane];
            }
            #pragma unroll
            for (int t = 0; t < 8; t++) {
                weh[t] = __shfl(eh, half * 8 + t);
                wel[t] = __shfl(el, half * 8 + t);
            }
            #pragma unroll
            for (int t = 0; t < 8; t++) {
                acc_h += weh[t] * lo_bf(u[t]);
                acc_l += wel[t] * hi_bf(u[t]);
            }
        }
        float r = 0.5f * (acc_h / rh + acc_l / rl);
        r = fminf(fmaxf(r, 0.0f), 6.0f);
        out[(size_t)node * 64 + lane] = r;
    }
}

// ================= Fallback path: R5 kernels (proven, 225.8 us) =================

__global__ __launch_bounds__(256) void k_gemm(
    const float* __restrict__ in, const float* __restrict__ Wh,
    const float* __restrict__ Wl, unsigned int* __restrict__ H)
{
    __shared__ __align__(16) unsigned short ldsW[2][64][136];
    __shared__ __align__(16) unsigned short ldsA[64][136];

    {
        int n  = threadIdx.x & 63;
        int kg = threadIdx.x >> 6;
        #pragma unroll
        for (int m = 0; m < 2; m++) {
            const float* W = m ? Wl : Wh;
            #pragma unroll
            for (int i = 0; i < 32; i += 2) {
                int k = kg * 32 + i;
                float a = W[k * 64 + n];
                float b = W[(k + 1) * 64 + n];
                *(unsigned int*)&ldsW[m][n][k] = packbf(a, b);
            }
        }
    }

    int wv = threadIdx.x >> 6;
    int lane = threadIdx.x & 63;
    int quad = lane >> 4, c = lane & 15;

    f32x4 av[8];
    int tile = blockIdx.x;
    if (tile >= TILES) return;

    {
        int row0B = tile * 64;
        const f32x4* src = (const f32x4*)(in + (size_t)row0B * IN_F);
        #pragma unroll
        for (int i = 0; i < 8; i++) {
            int cch = threadIdx.x + 256 * i;
            int row = cch >> 5;
            int kc = (cch & 31) * 4;
            int grow = row0B + row;
            av[i] = (grow < N_NODES) ? src[cch]
                    : *(const f32x4*)(in + (size_t)(N_NODES - 1) * IN_F + kc);
        }
    }

    for (; tile < TILES; tile += GEMM_GRID) {
        int row0B = tile * 64;

        __syncthreads();
        #pragma unroll
        for (int i = 0; i < 8; i++) {
            int cch = threadIdx.x + 256 * i;
            int row = cch >> 5;
            int kc = (cch & 31) * 4;
            *(unsigned int*)&ldsA[row][kc]     = packbf(av[i][0], av[i][1]);
            *(unsigned int*)&ldsA[row][kc + 2] = packbf(av[i][2], av[i][3]);
        }
        __syncthreads();

        int ntile = tile + GEMM_GRID;
        if (ntile < TILES) {
            int nrow0 = ntile * 64;
            const f32x4* src = (const f32x4*)(in + (size_t)nrow0 * IN_F);
            #pragma unroll
            for (int i = 0; i < 8; i++) {
                int cch = threadIdx.x + 256 * i;
                int row = cch >> 5;
                int kc = (cch & 31) * 4;
                int grow = nrow0 + row;
                av[i] = (grow < N_NODES) ? src[cch]
                        : *(const f32x4*)(in + (size_t)(N_NODES - 1) * IN_F + kc);
            }
        }

        bf16x8 afrag[4];
        #pragma unroll
        for (int kb = 0; kb < 4; kb++) {
            BF8 a;
            a.u = *(const u16x8*)&ldsA[wv * 16 + c][kb * 32 + quad * 8];
            afrag[kb] = a.b;
        }

        f32x4 acc[2][4];
        #pragma unroll
        for (int m = 0; m < 2; m++)
            #pragma unroll
            for (int t = 0; t < 4; t++) acc[m][t] = (f32x4){0, 0, 0, 0};

        #pragma unroll
        for (int kb = 0; kb < 4; kb++) {
            #pragma unroll
            for (int t = 0; t < 4; t++) {
                int n = t * 16 + c;
                BF8 bh, bl;
                bh.u = *(const u16x8*)&ldsW[0][n][kb * 32 + quad * 8];
                bl.u = *(const u16x8*)&ldsW[1][n][kb * 32 + quad * 8];
                acc[0][t] = __builtin_amdgcn_mfma_f32_16x16x32_bf16(afrag[kb], bh.b, acc[0][t], 0, 0, 0);
                acc[1][t] = __builtin_amdgcn_mfma_f32_16x16x32_bf16(afrag[kb], bl.b, acc[1][t], 0, 0, 0);
            }
        }

        int row0 = row0B + wv * 16;
        #pragma unroll
        for (int r = 0; r < 4; r++) {
            int row = row0 + quad * 4 + r;
            if (row >= N_NODES) continue;
            size_t base = (size_t)row * OUT_F + c;
            #pragma unroll
            for (int t = 0; t < 4; t++)
                H[base + t * 16] = packbf(acc[0][t][r], acc[1][t][r]);
        }
    }
}

__global__ __launch_bounds__(256) void k_agg(
    const unsigned int* __restrict__ H, const int* __restrict__ dst,
    const float* __restrict__ ah, const float* __restrict__ al,
    unsigned int* __restrict__ HAGG, f32x4* __restrict__ s)
{
    int lane = threadIdx.x & 63;
    int node = __builtin_amdgcn_readfirstlane(blockIdx.x * 4 + (threadIdx.x >> 6));
    const int* dp = dst + node * DEG;

    unsigned int hu = H[(size_t)node * 64 + lane];
    float hh = lo_bf(hu);
    float hl = hi_bf(hu);
    float sh = 16.0f * hh;
    float sl = 16.0f * hl;

    #pragma unroll
    for (int half = 0; half < 2; half++) {
        unsigned int u[8];
        #pragma unroll
        for (int t = 0; t < 8; t++) {
            int j = dp[half * 8 + t];
            u[t] = H[(size_t)j * 64 + lane];
        }
        #pragma unroll
        for (int t = 0; t < 8; t++) { sh += lo_bf(u[t]); sl -= hi_bf(u[t]); }
    }
    HAGG[(size_t)node * 64 + lane] = packbf(sh, sl);

    float ph = hh * ah[lane];
    float qh = hh * ah[64 + lane];
    float pl = hl * al[lane];
    float ql = hl * al[64 + lane];
    #pragma unroll
    for (int o = 32; o > 0; o >>= 1) {
        ph += __shfl_xor(ph, o);
        qh += __shfl_xor(qh, o);
        pl += __shfl_xor(pl, o);
        ql += __shfl_xor(ql, o);
    }
    if (lane == 0) s[node] = (f32x4){ph, qh, pl, ql};
}

__global__ __launch_bounds__(256) void k_out(
    const unsigned int* __restrict__ HAGG, const int* __restrict__ dst,
    const f32x4* __restrict__ s, float* __restrict__ out)
{
    int lane = threadIdx.x & 63;
    int node = __builtin_amdgcn_readfirstlane(blockIdx.x * 4 + (threadIdx.x >> 6));
    const int* dp = dst + node * DEG;

    int jl = dp[lane & 15];
    f32x4 si = s[node];
    f32x4 sj = s[jl];
    float xh = si.x + sj.y;
    float xl = si.z + sj.w;
    float lh = xh > 0.0f ? xh : 0.2f * xh;
    float ll = xl > 0.0f ? xl : 0.2f * xl;
    float wh = __expf(-lh);
    float wl = __expf(-ll);
    float rh = wh, rl = wl;
    #pragma unroll
    for (int o = 8; o > 0; o >>= 1) { rh += __shfl_xor(rh, o); rl += __shfl_xor(rl, o); }
    float eh = fminf(wh, 6.0f);
    float el = fminf(wl, 6.0f);

    float acc_h = 0.0f, acc_l = 0.0f;
    #pragma unroll
    for (int half = 0; half < 2; half++) {
        unsigned int u[8];
        float weh[8], wel[8];
        #pragma unroll
        for (int t = 0; t < 8; t++) {
            int j = dp[half * 8 + t];
            u[t] = HAGG[(size_t)j * 64 + lane];
        }
        #pragma unroll
        for (int t = 0; t < 8; t++) {
            weh[t] = __shfl(eh, half * 8 + t);
            wel[t] = __shfl(el, half * 8 + t);
        }
        #pragma unroll
        for (int t = 0; t < 8; t++) {
            acc_h += weh[t] * lo_bf(u[t]);
            acc_l += wel[t] * hi_bf(u[t]);
        }
    }
    float r = 0.5f * (acc_h / rh + acc_l / rl);
    r = fminf(fmaxf(r, 0.0f), 6.0f);
    out[(size_t)node * 64 + lane] = r;
}

extern "C" void kernel_launch(void* const* d_in, const int* in_sizes, int n_in,
                              void* d_out, int out_size, void* d_ws, size_t ws_size,
                              hipStream_t stream) {
    const float* input = (const float*)d_in[0];
    const int*   edge  = (const int*)d_in[1];     // [2, E]: src then dst
    const float* Wh    = (const float*)d_in[2];
    const float* Wl    = (const float*)d_in[3];
    const float* ah    = (const float*)d_in[4];
    const float* al    = (const float*)d_in[5];
    float* out = (float*)d_out;

    unsigned int* H    = (unsigned int*)d_ws;                    // 25.6 MB
    unsigned int* HAGG = H + (size_t)N_NODES * 64;               // 25.6 MB
    f32x4* s = (f32x4*)(HAGG + (size_t)N_NODES * 64);            // 1.6 MB

    const int* dstp = edge + E_EDGES;

    // Co-residency capacity for the fused cooperative kernel (cached; pure
    // host query — safe under graph capture).
    static int coopGrid = -1;
    if (coopGrid < 0) {
        int mb = 0;
        if (hipOccupancyMaxActiveBlocksPerMultiprocessor(
                &mb, reinterpret_cast<const void*>(&k_fused), 256, 0) != hipSuccess)
            mb = 0;
        coopGrid = mb * 256;                       // 256 CUs on MI355X
        if (coopGrid > 2048) coopGrid = 2048;
    }

    bool launched = false;
    if (coopGrid >= 256) {
        void* args[] = { (void*)&input, (void*)&Wh, (void*)&Wl, (void*)&dstp,
                         (void*)&ah, (void*)&al, (void*)&H, (void*)&HAGG,
                         (void*)&s, (void*)&out };
        if (hipLaunchCooperativeKernel(reinterpret_cast<const void*>(&k_fused),
                                       dim3(coopGrid), dim3(256),
                                       args, 0, stream) == hipSuccess)
            launched = true;
    }

    if (!launched) {   // proven R5 path
        k_gemm<<<GEMM_GRID, 256, 0, stream>>>(input, Wh, Wl, H);
        k_agg<<<N_NODES / 4, 256, 0, stream>>>(H, dstp, ah, al, HAGG, s);
        k_out<<<N_NODES / 4, 256, 0, stream>>>(HAGG, dstp, s, out);
    }
}

// Round 8
// 226.363 us; speedup vs baseline: 2.3143x; 2.3143x over previous
//
#include <hip/hip_runtime.h>

#define N_NODES 100000
#define DEG 16
#define IN_F 128
#define OUT_F 64
#define E_EDGES (N_NODES * DEG)
#define TILES 1563          // ceil(N_NODES / 64)

typedef __bf16 bf16x8 __attribute__((ext_vector_type(8)));
typedef unsigned short u16x8 __attribute__((ext_vector_type(8)));
typedef float f32x4 __attribute__((ext_vector_type(4)));
typedef unsigned int u32x4 __attribute__((ext_vector_type(4)));

union BF8 { u16x8 u; bf16x8 b; };

__device__ inline float lo_bf(unsigned int u) {
    union { unsigned int i; float f; } v; v.i = u << 16; return v.f;
}
__device__ inline float hi_bf(unsigned int u) {
    union { unsigned int i; float f; } v; v.i = u & 0xFFFF0000u; return v.f;
}
__device__ inline unsigned short f2bf(float f) {
    union { float f; unsigned int i; } v; v.f = f;
    return (unsigned short)((v.i + 0x7FFFu + ((v.i >> 16) & 1u)) >> 16);
}
__device__ inline unsigned int packbf(float a, float b) {
    return (unsigned int)f2bf(a) | ((unsigned int)f2bf(b) << 16);
}

// A fragment direct from global: 8 consecutive f32 -> bf16x8 (same f2bf bits
// as the ldsA path; verified correct end-to-end in R7's passing run)
__device__ inline bf16x8 mk_afrag(const float* ap) {
    f32x4 a0 = *(const f32x4*)ap;
    f32x4 a1 = *(const f32x4*)(ap + 4);
    BF8 r;
    r.u[0] = f2bf(a0[0]); r.u[1] = f2bf(a0[1]);
    r.u[2] = f2bf(a0[2]); r.u[3] = f2bf(a0[3]);
    r.u[4] = f2bf(a1[0]); r.u[5] = f2bf(a1[1]);
    r.u[6] = f2bf(a1[2]); r.u[7] = f2bf(a1[3]);
    return r.b;
}

// ---------------- Kernel A: GEMM with LDS-transposed coalesced epilogue ----
// Values stored are bit-identical to R3/R5 (same packbf(acc) bits); only the
// path to memory changes: ldsC transpose -> global_store_dwordx4 (4x256B
// contiguous segments per instruction, vs 16 scattered dword stores/thread).
__global__ __launch_bounds__(256) void k_gemm(
    const float* __restrict__ in, const float* __restrict__ Wh,
    const float* __restrict__ Wl, unsigned int* __restrict__ H)
{
    __shared__ __align__(16) unsigned short ldsW[2][64][136];  // 34816 B
    __shared__ unsigned int ldsC[64][66];                      // 16896 B (stride 66: <=2-way banks)

    // W conversion: coalesced 256-B reads along n; packed u32 LDS writes.
    {
        int n  = threadIdx.x & 63;
        int kg = threadIdx.x >> 6;
        #pragma unroll
        for (int m = 0; m < 2; m++) {
            const float* W = m ? Wl : Wh;
            #pragma unroll
            for (int i = 0; i < 32; i += 2) {
                int k = kg * 32 + i;
                float a = W[k * 64 + n];
                float b = W[(k + 1) * 64 + n];
                *(unsigned int*)&ldsW[m][n][k] = packbf(a, b);
            }
        }
    }
    __syncthreads();

    int wv = threadIdx.x >> 6;
    int lane = threadIdx.x & 63;
    int quad = lane >> 4, c = lane & 15;

    int row0B = blockIdx.x * 64;
    int arow = row0B + wv * 16 + c;
    const float* ap = in + (size_t)(arow < N_NODES ? arow : N_NODES - 1) * IN_F;

    bf16x8 afrag[4];
    #pragma unroll
    for (int kb = 0; kb < 4; kb++)
        afrag[kb] = mk_afrag(ap + kb * 32 + quad * 8);

    f32x4 acc[2][4];
    #pragma unroll
    for (int m = 0; m < 2; m++)
        #pragma unroll
        for (int t = 0; t < 4; t++) acc[m][t] = (f32x4){0, 0, 0, 0};

    #pragma unroll
    for (int kb = 0; kb < 4; kb++) {
        #pragma unroll
        for (int t = 0; t < 4; t++) {
            int n = t * 16 + c;
            BF8 bh, bl;
            bh.u = *(const u16x8*)&ldsW[0][n][kb * 32 + quad * 8];
            bl.u = *(const u16x8*)&ldsW[1][n][kb * 32 + quad * 8];
            acc[0][t] = __builtin_amdgcn_mfma_f32_16x16x32_bf16(afrag[kb], bh.b, acc[0][t], 0, 0, 0);
            acc[1][t] = __builtin_amdgcn_mfma_f32_16x16x32_bf16(afrag[kb], bl.b, acc[1][t], 0, 0, 0);
        }
    }

    // C/D: col = t*16 + c, row(local) = wv*16 + quad*4 + r  (proven mapping)
    #pragma unroll
    for (int r = 0; r < 4; r++) {
        int lrow = wv * 16 + quad * 4 + r;
        #pragma unroll
        for (int t = 0; t < 4; t++)
            ldsC[lrow][t * 16 + c] = packbf(acc[0][t][r], acc[1][t][r]);
    }
    __syncthreads();

    // coalesced store: thread -> one u32x4 (16 B) of one row; 16 lanes = full
    // 256-B row; 4 passes cover the 64x64 tile.
    #pragma unroll
    for (int p = 0; p < 4; p++) {
        int chunk = threadIdx.x + 256 * p;        // [0,1024)
        int row = chunk >> 4;
        int c4 = (chunk & 15) * 4;
        int grow = row0B + row;
        if (grow < N_NODES) {
            u32x4 v = { ldsC[row][c4], ldsC[row][c4 + 1],
                        ldsC[row][c4 + 2], ldsC[row][c4 + 3] };
            *(u32x4*)&H[(size_t)grow * OUT_F + c4] = v;
        }
    }
}

// ---------------- Kernel B: HAGG + attention scalars s (R3 verbatim) ----
__global__ __launch_bounds__(256) void k_agg(
    const unsigned int* __restrict__ H, const int* __restrict__ dst,
    const float* __restrict__ ah, const float* __restrict__ al,
    unsigned int* __restrict__ HAGG, f32x4* __restrict__ s)
{
    int lane = threadIdx.x & 63;
    int node = __builtin_amdgcn_readfirstlane(blockIdx.x * 4 + (threadIdx.x >> 6));
    const int* dp = dst + node * DEG;   // 64-B aligned row, scalar loads

    unsigned int hu = H[(size_t)node * 64 + lane];
    float hh = lo_bf(hu);
    float hl = hi_bf(hu);
    float sh = 16.0f * hh;   // DEG * h[i] (self-loop among the 16 dst)
    float sl = 16.0f * hl;

    #pragma unroll
    for (int half = 0; half < 2; half++) {
        unsigned int u[8];
        #pragma unroll
        for (int t = 0; t < 8; t++) {
            int j = dp[half * 8 + t];                 // SGPR
            u[t] = H[(size_t)j * 64 + lane];          // 8 independent loads in flight
        }
        #pragma unroll
        for (int t = 0; t < 8; t++) { sh += lo_bf(u[t]); sl -= hi_bf(u[t]); }
    }
    HAGG[(size_t)node * 64 + lane] = packbf(sh, sl);

    float ph = hh * ah[lane];
    float qh = hh * ah[64 + lane];
    float pl = hl * al[lane];
    float ql = hl * al[64 + lane];
    #pragma unroll
    for (int o = 32; o > 0; o >>= 1) {
        ph += __shfl_xor(ph, o);
        qh += __shfl_xor(qh, o);
        pl += __shfl_xor(pl, o);
        ql += __shfl_xor(ql, o);
    }
    if (lane == 0) s[node] = (f32x4){ph, qh, pl, ql};
}

// ---------------- Kernel C: weighted aggregate + relu6 (R3 verbatim) ----
__global__ __launch_bounds__(256) void k_out(
    const unsigned int* __restrict__ HAGG, const int* __restrict__ dst,
    const f32x4* __restrict__ s, float* __restrict__ out)
{
    int lane = threadIdx.x & 63;
    int node = __builtin_amdgcn_readfirstlane(blockIdx.x * 4 + (threadIdx.x >> 6));
    const int* dp = dst + node * DEG;

    int jl = dp[lane & 15];                   // lane e<16 owns edge e
    f32x4 si = s[node];                       // wave-uniform
    f32x4 sj = s[jl];
    float xh = si.x + sj.y;                   // p_high[i] + q_high[j]
    float xl = si.z + sj.w;
    float lh = xh > 0.0f ? xh : 0.2f * xh;
    float ll = xl > 0.0f ? xl : 0.2f * xl;
    float wh = __expf(-lh);
    float wl = __expf(-ll);
    float rh = wh, rl = wl;                   // rowsum over RAW exp values
    #pragma unroll
    for (int o = 8; o > 0; o >>= 1) { rh += __shfl_xor(rh, o); rl += __shfl_xor(rl, o); }
    float eh = fminf(wh, 6.0f);               // relu6 on weights
    float el = fminf(wl, 6.0f);

    float acc_h = 0.0f, acc_l = 0.0f;
    #pragma unroll
    for (int half = 0; half < 2; half++) {
        unsigned int u[8];
        float weh[8], wel[8];
        #pragma unroll
        for (int t = 0; t < 8; t++) {
            int j = dp[half * 8 + t];                 // SGPR
            u[t] = HAGG[(size_t)j * 64 + lane];       // 8 independent loads in flight
        }
        #pragma unroll
        for (int t = 0; t < 8; t++) {
            weh[t] = __shfl(eh, half * 8 + t);
            wel[t] = __shfl(el, half * 8 + t);
        }
        #pragma unroll
        for (int t = 0; t < 8; t++) {
            acc_h += weh[t] * lo_bf(u[t]);
            acc_l += wel[t] * hi_bf(u[t]);
        }
    }
    float r = 0.5f * (acc_h / rh + acc_l / rl);
    r = fminf(fmaxf(r, 0.0f), 6.0f);
    out[(size_t)node * 64 + lane] = r;
}

extern "C" void kernel_launch(void* const* d_in, const int* in_sizes, int n_in,
                              void* d_out, int out_size, void* d_ws, size_t ws_size,
                              hipStream_t stream) {
    const float* input = (const float*)d_in[0];
    const int*   edge  = (const int*)d_in[1];     // [2, E]: src then dst
    const float* Wh    = (const float*)d_in[2];
    const float* Wl    = (const float*)d_in[3];
    const float* ah    = (const float*)d_in[4];
    const float* al    = (const float*)d_in[5];
    float* out = (float*)d_out;

    unsigned int* H    = (unsigned int*)d_ws;                    // 25.6 MB
    unsigned int* HAGG = H + (size_t)N_NODES * 64;               // 25.6 MB
    f32x4* s = (f32x4*)(HAGG + (size_t)N_NODES * 64);            // 1.6 MB

    const int* dstp = edge + E_EDGES;

    k_gemm<<<TILES, 256, 0, stream>>>(input, Wh, Wl, H);
    k_agg<<<N_NODES / 4, 256, 0, stream>>>(H, dstp, ah, al, HAGG, s);
    k_out<<<N_NODES / 4, 256, 0, stream>>>(HAGG, dstp, s, out);
}